// Round 4
// baseline (1480.687 us; speedup 1.0000x reference)
//
#include <hip/hip_runtime.h>
#include <math.h>

// ---------------------------------------------------------------------------
// MultiModalGraphSAGE — MFMA split-bf16 pipeline, R4.
// R3 post-mortem: GEMMs latency-bound (MfmaUtil 7%, VALU 9%, HBM 10%).
// R4: compile-time K (full unroll), hoisted B base pointers (immediate k
// offsets), 64-row blocks (1 m-tile/wave -> 2x waves/CU), bf16 gather planes
// for both aggregations (halves gather bytes).
// ---------------------------------------------------------------------------

#define EPS 1e-5f

typedef __attribute__((ext_vector_type(8))) short bf16x8;
typedef __attribute__((ext_vector_type(4))) float f32x4;

__device__ inline unsigned short f2bf(float x) {
    unsigned u = __float_as_uint(x);
    u += 0x7fff + ((u >> 16) & 1);          // RNE to bf16
    return (unsigned short)(u >> 16);
}
__device__ inline float bf2f(unsigned short h) {
    return __uint_as_float(((unsigned)h) << 16);
}

// ---------------- CSR build ----------------

__global__ void zero_int(int* __restrict__ p, int n) {
    int i = blockIdx.x * 256 + threadIdx.x;
    if (i < n) p[i] = 0;
}

__global__ void count_deg(const int* __restrict__ dst, int* __restrict__ deg, int e) {
    int i = blockIdx.x * 256 + threadIdx.x;
    if (i < e) atomicAdd(&deg[dst[i]], 1);
}

// pass 1: per-block local exclusive scan (1024 elems/block) + block totals
__global__ __launch_bounds__(1024)
void scan_block(const int* __restrict__ deg, int* __restrict__ rowptr,
                int* __restrict__ part, int n) {
    __shared__ int buf[1024];
    const int tid = threadIdx.x;
    const int i = blockIdx.x * 1024 + tid;
    const int v = (i < n) ? deg[i] : 0;
    buf[tid] = v;
    __syncthreads();
    #pragma unroll 1
    for (int off = 1; off < 1024; off <<= 1) {
        int t = (tid >= off) ? buf[tid - off] : 0;
        __syncthreads();
        buf[tid] += t;
        __syncthreads();
    }
    if (i < n) rowptr[i] = buf[tid] - v;          // local exclusive
    if (tid == 1023) part[blockIdx.x] = buf[1023];
}

// pass 2: exclusive scan of block partials (nb <= 1024), part[nb] = total
__global__ __launch_bounds__(1024)
void scan_part(int* __restrict__ part, int nb) {
    __shared__ int buf[1024];
    const int tid = threadIdx.x;
    const int v = (tid < nb) ? part[tid] : 0;
    buf[tid] = v;
    __syncthreads();
    #pragma unroll 1
    for (int off = 1; off < 1024; off <<= 1) {
        int t = (tid >= off) ? buf[tid - off] : 0;
        __syncthreads();
        buf[tid] += t;
        __syncthreads();
    }
    if (tid < nb) part[tid] = buf[tid] - v;       // exclusive
    if (tid == 1023) part[nb] = buf[1023];        // grand total
}

// pass 3: add block offsets; also seed cursor[] (fused copy) and rowptr[n]
__global__ void scan_add(const int* __restrict__ part, int* __restrict__ rowptr,
                         int* __restrict__ cursor, int n, int nb) {
    int i = blockIdx.x * 256 + threadIdx.x;
    if (i < n) {
        int v = rowptr[i] + part[i >> 10];
        rowptr[i] = v;
        cursor[i] = v;
    }
    if (i == 0) rowptr[n] = part[nb];
}

__global__ void fill_edges(const int* __restrict__ src, const int* __restrict__ dst,
                           int* __restrict__ cursor, int* __restrict__ eidx, int e) {
    int i = blockIdx.x * 256 + threadIdx.x;
    if (i < e) {
        int pos = atomicAdd(&cursor[dst[i]], 1);
        eidx[pos] = src[i];
    }
}

// ---------------- weight prep: W[K][N] fp32 -> Wt hi/lo [N][ldt] bf16 -------

__global__ void prep_w(const float* __restrict__ W, int K, int N,
                       short* __restrict__ hi, short* __restrict__ lo,
                       int ldt, int koff) {
    int i = blockIdx.x * 256 + threadIdx.x;
    if (i >= K * N) return;
    int k = i / N, n = i - k * N;
    float x = W[i];
    unsigned short h = f2bf(x);
    unsigned short l = f2bf(x - bf2f(h));
    size_t o = (size_t)n * ldt + koff + k;
    hi[o] = (short)h;
    lo[o] = (short)l;
}

// ---------------- mean aggregation over CSR, bf16 gather plane --------------
// featb: [n][128] bf16. One wave per node; lane holds 2 channels (as uint).
// if addsrc != null: out = relu(bn(addsrc + mean + bias))  (sage1 combine)
__global__ __launch_bounds__(256)
void agg_mean_bf(const short* __restrict__ featb,
                 const int* __restrict__ rowptr, const int* __restrict__ eidx,
                 const float* __restrict__ addsrc, int lds_,
                 const float* __restrict__ bias,
                 const float* __restrict__ bng, const float* __restrict__ bnb,
                 const float* __restrict__ bnm, const float* __restrict__ bnv,
                 float* __restrict__ out, int ldo, int n) {
    const int node = blockIdx.x * 4 + (threadIdx.x >> 6);
    if (node >= n) return;
    const int lane = threadIdx.x & 63;
    const int beg = rowptr[node], end = rowptr[node + 1];
    float sx = 0.f, sy = 0.f;
    for (int e = beg; e < end; ++e) {
        const unsigned v =
            ((const unsigned*)(featb + (size_t)eidx[e] * 128))[lane];
        sx += __uint_as_float(v << 16);            // even channel
        sy += __uint_as_float(v & 0xffff0000u);    // odd channel
    }
    const float inv = 1.0f / fmaxf((float)(end - beg), 1.0f);
    sx *= inv; sy *= inv;
    if (addsrc) {
        const int c = lane * 2;
        const float2 s = ((const float2*)(addsrc + (size_t)node * lds_))[lane];
        float v0 = s.x + sx + bias[c];
        float v1 = s.y + sy + bias[c + 1];
        v0 = (v0 - bnm[c])     * (bng[c]     / sqrtf(bnv[c]     + EPS)) + bnb[c];
        v1 = (v1 - bnm[c + 1]) * (bng[c + 1] / sqrtf(bnv[c + 1] + EPS)) + bnb[c + 1];
        sx = fmaxf(v0, 0.f);
        sy = fmaxf(v1, 0.f);
    }
    ((float2*)(out + (size_t)node * ldo))[lane] = make_float2(sx, sy);
}

// ---------------- MFMA GEMM, LDS-free, split-bf16, compile-time K -----------
// Block: 256 thr = 4 waves, each wave one 16-row m-tile (64 rows/block).
// NT n-tiles of 16x16x32. A: fp32 [M][lda] (dual source concat on K).
// B: Wt hi/lo bf16 [Nw][K] row-major. C: fp32 (cols < fpN) and optional
// bf16 plane bfout[M][128] for cols >= bfcol0.
template<int NT, int K1, int K2>
__global__ __launch_bounds__(256, 4)
void gemm_mfma(const float* __restrict__ A1, int lda1,
               const float* __restrict__ A2, int lda2,
               const short* __restrict__ Wt_hi, const short* __restrict__ Wt_lo,
               const float* __restrict__ bias,
               const float* __restrict__ bng, const float* __restrict__ bnb,
               const float* __restrict__ bnm, const float* __restrict__ bnv,
               int relu,
               float* __restrict__ C, int fpN, int ldc,
               short* __restrict__ bfout, int bfcol0, int M) {
    constexpr int K = K1 + K2;                   // multiple of 32
    const int tid  = threadIdx.x;
    const int lane = tid & 63;
    const int wv   = tid >> 6;
    const int bm   = blockIdx.y * 64;
    const int col0 = blockIdx.x * (NT * 16);
    const int lrow = lane & 15;                  // A row / C col within tile
    const int quad = lane >> 4;                  // 0..3
    const int kin  = quad * 8;                   // k offset within 32-chunk

    const int arow = min(bm + wv * 16 + lrow, M - 1);
    const float* pA1 = A1 + (size_t)arow * lda1 + kin;
    const float* pA2 = (K2 > 0) ? (A2 + (size_t)arow * lda2 + kin) : nullptr;

    const short* pBh[NT];
    const short* pBl[NT];
    #pragma unroll
    for (int nt = 0; nt < NT; ++nt) {
        const size_t wo = (size_t)(col0 + nt * 16 + lrow) * K + kin;
        pBh[nt] = Wt_hi + wo;
        pBl[nt] = Wt_lo + wo;
    }

    f32x4 acc[NT];
    #pragma unroll
    for (int nt = 0; nt < NT; ++nt) acc[nt] = (f32x4){0.f, 0.f, 0.f, 0.f};

    #pragma unroll
    for (int c = 0; c < K / 32; ++c) {
        const float* p = (c * 32 < K1) ? (pA1 + c * 32) : (pA2 + (c * 32 - K1));
        const float4 f0 = *(const float4*)p;
        const float4 f1 = *(const float4*)(p + 4);
        const float f[8] = {f0.x, f0.y, f0.z, f0.w, f1.x, f1.y, f1.z, f1.w};
        bf16x8 ah, al;
        #pragma unroll
        for (int j = 0; j < 8; ++j) {
            const unsigned short hu = f2bf(f[j]);
            ah[j] = (short)hu;
            al[j] = (short)f2bf(f[j] - bf2f(hu));
        }
        #pragma unroll
        for (int nt = 0; nt < NT; ++nt) {
            const bf16x8 bh = *(const bf16x8*)(pBh[nt] + c * 32);
            const bf16x8 bl = *(const bf16x8*)(pBl[nt] + c * 32);
            acc[nt] = __builtin_amdgcn_mfma_f32_16x16x32_bf16(ah, bh, acc[nt], 0, 0, 0);
            acc[nt] = __builtin_amdgcn_mfma_f32_16x16x32_bf16(ah, bl, acc[nt], 0, 0, 0);
            acc[nt] = __builtin_amdgcn_mfma_f32_16x16x32_bf16(al, bh, acc[nt], 0, 0, 0);
        }
    }

    // epilogue: C/D layout col=lane&15, row=quad*4+reg
    const int rbase = bm + wv * 16 + quad * 4;
    #pragma unroll
    for (int nt = 0; nt < NT; ++nt) {
        const int gcol = col0 + nt * 16 + lrow;
        const float bsc = bias ? bias[gcol] : 0.f;
        float g = 1.f, bb = 0.f, mm = 0.f;
        if (bng) { g = bng[gcol] / sqrtf(bnv[gcol] + EPS); bb = bnb[gcol]; mm = bnm[gcol]; }
        #pragma unroll
        for (int r = 0; r < 4; ++r) {
            const int grow = rbase + r;
            if (grow >= M) continue;
            float x = acc[nt][r] + bsc;
            if (bng) x = (x - mm) * g + bb;
            if (relu) x = fmaxf(x, 0.f);
            if (gcol < fpN) C[(size_t)grow * ldc + gcol] = x;
            if (bfout && gcol >= bfcol0)
                bfout[(size_t)grow * 128 + (gcol - bfcol0)] = (short)f2bf(x);
        }
    }
}

// ---------------------------------------------------------------------------

extern "C" void kernel_launch(void* const* d_in, const int* in_sizes, int n_in,
                              void* d_out, int out_size, void* d_ws, size_t ws_size,
                              hipStream_t stream) {
    const float* sf    = (const float*)d_in[0];
    const float* mf    = (const float*)d_in[1];
    const int*   src   = (const int*)d_in[2];
    const int*   dst   = (const int*)d_in[3];
    const float* enc_w = (const float*)d_in[4];
    const float* enc_b = (const float*)d_in[5];
    const float* s0_ws = (const float*)d_in[6];
    const float* s0_wn = (const float*)d_in[7];
    const float* s0_b  = (const float*)d_in[8];
    const float* bn0_g = (const float*)d_in[9];
    const float* bn0_b = (const float*)d_in[10];
    const float* bn0_m = (const float*)d_in[11];
    const float* bn0_v = (const float*)d_in[12];
    const float* s1_ws = (const float*)d_in[13];
    const float* s1_wn = (const float*)d_in[14];
    const float* s1_b  = (const float*)d_in[15];
    const float* bn1_g = (const float*)d_in[16];
    const float* bn1_b = (const float*)d_in[17];
    const float* bn1_m = (const float*)d_in[18];
    const float* bn1_v = (const float*)d_in[19];
    const float* rel_w = (const float*)d_in[20];
    const float* rel_b = (const float*)d_in[21];
    const float* cw1   = (const float*)d_in[22];
    const float* cb1   = (const float*)d_in[23];
    const float* cw2   = (const float*)d_in[24];
    const float* cb2   = (const float*)d_in[25];
    float* out = (float*)d_out;

    const int nn = in_sizes[0] / 128;   // 100000
    const int ne = in_sizes[2];         // 800000
    const int nb = (nn + 1023) / 1024;  // scan blocks (98)

    // workspace layout
    float* h0 = (float*)d_ws;                    // [nn,128]  h0 (live to end)
    float* h1 = h0 + (size_t)nn * 128;           // [nn,256]  h1 -> h2(ld128) | o1
    float* st = h1 + (size_t)nn * 256;           // [nn,128]  agg0 -> s1 -> r
    short* h0b = (short*)(st + (size_t)nn * 128);// [nn,128] bf16 plane of h0
    short* t1b = h0b + (size_t)nn * 128;         // [nn,128] bf16 plane of t1
    int* deg    = (int*)(t1b + (size_t)nn * 128);
    int* rowptr = deg + nn;
    int* cursor = rowptr + nn + 1;
    int* part   = cursor + nn;                   // [nb+1]
    int* eidx   = part + nb + 1;
    // bf16 weight planes (hi, lo) — transposed [N][K]
    short* wts = (short*)(eidx + ne);
    short* wt_enc_h = wts;                 short* wt_enc_l = wt_enc_h + 65536;   // [128][512]
    short* wt_s0_h  = wt_enc_l + 65536;    short* wt_s0_l  = wt_s0_h  + 65536;   // [256][256]
    short* wt_st_h  = wt_s0_l  + 65536;    short* wt_st_l  = wt_st_h  + 65536;   // [256][256]
    short* wt_rel_h = wt_st_l  + 65536;    short* wt_rel_l = wt_rel_h + 32768;   // [128][256]
    short* wt_c1_h  = wt_rel_l + 32768;    short* wt_c1_l  = wt_c1_h  + 8192;    // [64][128]
    short* wt_c2_h  = wt_c1_l  + 8192;     short* wt_c2_l  = wt_c2_h  + 2048;    // [32][64]

    const dim3 blk(256);
    const int gM = (nn + 63) / 64;      // 1563 row-blocks

    // --- CSR build (parallel scan) ---
    zero_int  <<<dim3((nn + 255) / 256), blk, 0, stream>>>(deg, nn);
    count_deg <<<dim3((ne + 255) / 256), blk, 0, stream>>>(dst, deg, ne);
    scan_block<<<dim3(nb), dim3(1024), 0, stream>>>(deg, rowptr, part, nn);
    scan_part <<<dim3(1),  dim3(1024), 0, stream>>>(part, nb);
    scan_add  <<<dim3((nn + 255) / 256), blk, 0, stream>>>(part, rowptr, cursor, nn, nb);
    fill_edges<<<dim3((ne + 255) / 256), blk, 0, stream>>>(src, dst, cursor, eidx, ne);

    // --- weight prep (tiny) ---
    prep_w<<<dim3(256), blk, 0, stream>>>(enc_w, 512, 128, wt_enc_h, wt_enc_l, 512, 0);
    prep_w<<<dim3(128), blk, 0, stream>>>(s0_ws, 128, 256, wt_s0_h, wt_s0_l, 256, 0);
    prep_w<<<dim3(128), blk, 0, stream>>>(s0_wn, 128, 256, wt_s0_h, wt_s0_l, 256, 128);
    prep_w<<<dim3(128), blk, 0, stream>>>(s1_ws, 256, 128, wt_st_h, wt_st_l, 256, 0);
    prep_w<<<dim3(128), blk, 0, stream>>>(s1_wn, 256, 128, wt_st_h + (size_t)128 * 256,
                                          wt_st_l + (size_t)128 * 256, 256, 0);
    prep_w<<<dim3(128), blk, 0, stream>>>(rel_w, 256, 128, wt_rel_h, wt_rel_l, 256, 0);
    prep_w<<<dim3(32),  blk, 0, stream>>>(cw1, 128, 64, wt_c1_h, wt_c1_l, 128, 0);
    prep_w<<<dim3(8),   blk, 0, stream>>>(cw2, 64, 32, wt_c2_h, wt_c2_l, 64, 0);

    // --- h0 = relu(concat(sf,mf) @ enc_w + enc_b); also bf16 plane h0b ---
    gemm_mfma<8, 128, 384><<<dim3(1, gM), blk, 0, stream>>>(
        sf, 128, mf, 384, wt_enc_h, wt_enc_l, enc_b,
        nullptr, nullptr, nullptr, nullptr, 1, h0, 128, 128, h0b, 0, nn);

    // --- agg0 = mean_neigh(h0) -> st (bf16 gather) ---
    agg_mean_bf<<<dim3((nn + 3) / 4), blk, 0, stream>>>(
        h0b, rowptr, eidx, nullptr, 0, nullptr,
        nullptr, nullptr, nullptr, nullptr, st, 128, nn);

    // --- h1 = relu(bn0(h0@ws0 + agg0@wn0 + b0)) ---
    gemm_mfma<8, 128, 128><<<dim3(2, gM), blk, 0, stream>>>(
        h0, 128, st, 128, wt_s0_h, wt_s0_l, s0_b,
        bn0_g, bn0_b, bn0_m, bn0_v, 1, h1, 256, 256, nullptr, 0, nn);

    // --- [s1 | t1] = h1 @ [ws1 | wn1]; s1 fp32 -> st, t1 bf16 -> t1b ---
    gemm_mfma<8, 256, 0><<<dim3(2, gM), blk, 0, stream>>>(
        h1, 256, nullptr, 0, wt_st_h, wt_st_l, nullptr,
        nullptr, nullptr, nullptr, nullptr, 0, st, 128, 128, t1b, 128, nn);

    // --- h2 = relu(bn1(s1 + mean_neigh(t1) + b1)) -> h1[0:nn*128] (ld128) ---
    agg_mean_bf<<<dim3((nn + 3) / 4), blk, 0, stream>>>(
        t1b, rowptr, eidx, st, 128, s1_b,
        bn1_g, bn1_b, bn1_m, bn1_v, h1, 128, nn);

    // --- r = relu(h0@rel_w[:128] + h2@rel_w[128:] + rel_b) -> st ---
    gemm_mfma<8, 128, 128><<<dim3(1, gM), blk, 0, stream>>>(
        h0, 128, h1, 128, wt_rel_h, wt_rel_l, rel_b,
        nullptr, nullptr, nullptr, nullptr, 1, st, 128, 128, nullptr, 0, nn);

    // --- o1 = relu(r@cls_w1 + cb1) -> h1 + nn*128 ([nn,64]) ---
    gemm_mfma<4, 128, 0><<<dim3(1, gM), blk, 0, stream>>>(
        st, 128, nullptr, 0, wt_c1_h, wt_c1_l, cb1,
        nullptr, nullptr, nullptr, nullptr, 1, h1 + (size_t)nn * 128, 64, 64,
        nullptr, 0, nn);

    // --- out = o1@cls_w2 + cb2 -> d_out [nn,32] ---
    gemm_mfma<2, 64, 0><<<dim3(1, gM), blk, 0, stream>>>(
        h1 + (size_t)nn * 128, 64, nullptr, 0, wt_c2_h, wt_c2_l, cb2,
        nullptr, nullptr, nullptr, nullptr, 0, out, 32, 32, nullptr, 0, nn);
}

// Round 5
// 1355.359 us; speedup vs baseline: 1.0925x; 1.0925x over previous
//
#include <hip/hip_runtime.h>
#include <math.h>

// ---------------------------------------------------------------------------
// MultiModalGraphSAGE — MFMA split-bf16 pipeline, R5.
// R4 post-mortem: 64-row blocks + flat unroll made scheduler serialize loads
// (VGPR 56, MfmaUtil 5%). R5: back to 128-row blocks (2 m-tiles/wave, 4 waves)
// with EXPLICIT register double-buffering of the next K-chunk's A (fp32 raw)
// and B (bf16 hi/lo) fragments, compile-time K. bf16 gather planes kept.
// ---------------------------------------------------------------------------

#define EPS 1e-5f

typedef __attribute__((ext_vector_type(8))) short bf16x8;
typedef __attribute__((ext_vector_type(4))) float f32x4;

__device__ inline unsigned short f2bf(float x) {
    unsigned u = __float_as_uint(x);
    u += 0x7fff + ((u >> 16) & 1);          // RNE to bf16
    return (unsigned short)(u >> 16);
}
__device__ inline float bf2f(unsigned short h) {
    return __uint_as_float(((unsigned)h) << 16);
}

// ---------------- CSR build ----------------

__global__ void zero_int(int* __restrict__ p, int n) {
    int i = blockIdx.x * 256 + threadIdx.x;
    if (i < n) p[i] = 0;
}

__global__ void count_deg(const int* __restrict__ dst, int* __restrict__ deg, int e) {
    int i = blockIdx.x * 256 + threadIdx.x;
    if (i < e) atomicAdd(&deg[dst[i]], 1);
}

// pass 1: per-block local exclusive scan (1024 elems/block) + block totals
__global__ __launch_bounds__(1024)
void scan_block(const int* __restrict__ deg, int* __restrict__ rowptr,
                int* __restrict__ part, int n) {
    __shared__ int buf[1024];
    const int tid = threadIdx.x;
    const int i = blockIdx.x * 1024 + tid;
    const int v = (i < n) ? deg[i] : 0;
    buf[tid] = v;
    __syncthreads();
    #pragma unroll 1
    for (int off = 1; off < 1024; off <<= 1) {
        int t = (tid >= off) ? buf[tid - off] : 0;
        __syncthreads();
        buf[tid] += t;
        __syncthreads();
    }
    if (i < n) rowptr[i] = buf[tid] - v;          // local exclusive
    if (tid == 1023) part[blockIdx.x] = buf[1023];
}

// pass 2: exclusive scan of block partials (nb <= 1024), part[nb] = total
__global__ __launch_bounds__(1024)
void scan_part(int* __restrict__ part, int nb) {
    __shared__ int buf[1024];
    const int tid = threadIdx.x;
    const int v = (tid < nb) ? part[tid] : 0;
    buf[tid] = v;
    __syncthreads();
    #pragma unroll 1
    for (int off = 1; off < 1024; off <<= 1) {
        int t = (tid >= off) ? buf[tid - off] : 0;
        __syncthreads();
        buf[tid] += t;
        __syncthreads();
    }
    if (tid < nb) part[tid] = buf[tid] - v;       // exclusive
    if (tid == 1023) part[nb] = buf[1023];        // grand total
}

// pass 3: add block offsets; also seed cursor[] (fused copy) and rowptr[n]
__global__ void scan_add(const int* __restrict__ part, int* __restrict__ rowptr,
                         int* __restrict__ cursor, int n, int nb) {
    int i = blockIdx.x * 256 + threadIdx.x;
    if (i < n) {
        int v = rowptr[i] + part[i >> 10];
        rowptr[i] = v;
        cursor[i] = v;
    }
    if (i == 0) rowptr[n] = part[nb];
}

__global__ void fill_edges(const int* __restrict__ src, const int* __restrict__ dst,
                           int* __restrict__ cursor, int* __restrict__ eidx, int e) {
    int i = blockIdx.x * 256 + threadIdx.x;
    if (i < e) {
        int pos = atomicAdd(&cursor[dst[i]], 1);
        eidx[pos] = src[i];
    }
}

// ---------------- weight prep: W[K][N] fp32 -> Wt hi/lo [N][ldt] bf16 -------

__global__ void prep_w(const float* __restrict__ W, int K, int N,
                       short* __restrict__ hi, short* __restrict__ lo,
                       int ldt, int koff) {
    int i = blockIdx.x * 256 + threadIdx.x;
    if (i >= K * N) return;
    int k = i / N, n = i - k * N;
    float x = W[i];
    unsigned short h = f2bf(x);
    unsigned short l = f2bf(x - bf2f(h));
    size_t o = (size_t)n * ldt + koff + k;
    hi[o] = (short)h;
    lo[o] = (short)l;
}

// ---------------- mean aggregation over CSR, bf16 gather plane --------------
__global__ __launch_bounds__(256)
void agg_mean_bf(const short* __restrict__ featb,
                 const int* __restrict__ rowptr, const int* __restrict__ eidx,
                 const float* __restrict__ addsrc, int lds_,
                 const float* __restrict__ bias,
                 const float* __restrict__ bng, const float* __restrict__ bnb,
                 const float* __restrict__ bnm, const float* __restrict__ bnv,
                 float* __restrict__ out, int ldo, int n) {
    const int node = blockIdx.x * 4 + (threadIdx.x >> 6);
    if (node >= n) return;
    const int lane = threadIdx.x & 63;
    const int beg = rowptr[node], end = rowptr[node + 1];
    float sx = 0.f, sy = 0.f;
    for (int e = beg; e < end; ++e) {
        const unsigned v =
            ((const unsigned*)(featb + (size_t)eidx[e] * 128))[lane];
        sx += __uint_as_float(v << 16);            // even channel
        sy += __uint_as_float(v & 0xffff0000u);    // odd channel
    }
    const float inv = 1.0f / fmaxf((float)(end - beg), 1.0f);
    sx *= inv; sy *= inv;
    if (addsrc) {
        const int c = lane * 2;
        const float2 s = ((const float2*)(addsrc + (size_t)node * lds_))[lane];
        float v0 = s.x + sx + bias[c];
        float v1 = s.y + sy + bias[c + 1];
        v0 = (v0 - bnm[c])     * (bng[c]     / sqrtf(bnv[c]     + EPS)) + bnb[c];
        v1 = (v1 - bnm[c + 1]) * (bng[c + 1] / sqrtf(bnv[c + 1] + EPS)) + bnb[c + 1];
        sx = fmaxf(v0, 0.f);
        sy = fmaxf(v1, 0.f);
    }
    ((float2*)(out + (size_t)node * ldo))[lane] = make_float2(sx, sy);
}

// ---------------- MFMA GEMM, LDS-free, split-bf16, reg double-buffer --------
// Block: 256 thr = 4 waves, each wave 2 m-tiles (128 rows/block). NT n-tiles.
// Compile-time K1/K2; K-chunk loop explicitly double-buffers next chunk's raw
// A (fp32) and B (bf16 hi/lo) in registers so all loads batch-issue ahead of
// the MFMA block. C: fp32 cols < fpN, optional bf16 plane for cols >= bfcol0.
template<int NT, int K1, int K2>
__global__ __launch_bounds__(256)
void gemm_mfma(const float* __restrict__ A1, int lda1,
               const float* __restrict__ A2, int lda2,
               const short* __restrict__ Wt_hi, const short* __restrict__ Wt_lo,
               const float* __restrict__ bias,
               const float* __restrict__ bng, const float* __restrict__ bnb,
               const float* __restrict__ bnm, const float* __restrict__ bnv,
               int relu,
               float* __restrict__ C, int fpN, int ldc,
               short* __restrict__ bfout, int bfcol0, int M) {
    constexpr int K  = K1 + K2;                  // multiple of 32
    constexpr int NC = K / 32;                   // chunk count
    const int tid  = threadIdx.x;
    const int lane = tid & 63;
    const int wv   = tid >> 6;
    const int bm   = blockIdx.y * 128;
    const int col0 = blockIdx.x * (NT * 16);
    const int lrow = lane & 15;                  // A row / C col within tile
    const int quad = lane >> 4;                  // 0..3
    const int kin  = quad * 8;                   // k offset within 32-chunk

    const float* pA1[2];
    const float* pA2[2];
    #pragma unroll
    for (int m = 0; m < 2; ++m) {
        const int ar = min(bm + wv * 32 + m * 16 + lrow, M - 1);
        pA1[m] = A1 + (size_t)ar * lda1 + kin;
        pA2[m] = (K2 > 0) ? (A2 + (size_t)ar * lda2 + kin) : nullptr;
    }

    const short* pBh[NT];
    const short* pBl[NT];
    #pragma unroll
    for (int nt = 0; nt < NT; ++nt) {
        const size_t wo = (size_t)(col0 + nt * 16 + lrow) * K + kin;
        pBh[nt] = Wt_hi + wo;
        pBl[nt] = Wt_lo + wo;
    }

    f32x4 acc[2][NT];
    #pragma unroll
    for (int m = 0; m < 2; ++m)
        #pragma unroll
        for (int nt = 0; nt < NT; ++nt)
            acc[m][nt] = (f32x4){0.f, 0.f, 0.f, 0.f};

    // ---- register double buffers ----
    float4 a_nx[2][2];
    bf16x8 bh_nx[NT], bl_nx[NT];

    #pragma unroll
    for (int m = 0; m < 2; ++m) {
        a_nx[m][0] = *(const float4*)(pA1[m]);
        a_nx[m][1] = *(const float4*)(pA1[m] + 4);
    }
    #pragma unroll
    for (int nt = 0; nt < NT; ++nt) {
        bh_nx[nt] = *(const bf16x8*)(pBh[nt]);
        bl_nx[nt] = *(const bf16x8*)(pBl[nt]);
    }

    #pragma unroll
    for (int c = 0; c < NC; ++c) {
        // consume current
        float4 a_c[2][2];
        bf16x8 bh_c[NT], bl_c[NT];
        #pragma unroll
        for (int m = 0; m < 2; ++m) { a_c[m][0] = a_nx[m][0]; a_c[m][1] = a_nx[m][1]; }
        #pragma unroll
        for (int nt = 0; nt < NT; ++nt) { bh_c[nt] = bh_nx[nt]; bl_c[nt] = bl_nx[nt]; }

        // prefetch next chunk (batched: issued before this chunk's MFMAs)
        if (c + 1 < NC) {
            const int k = (c + 1) * 32;
            #pragma unroll
            for (int m = 0; m < 2; ++m) {
                const float* p = (k < K1) ? (pA1[m] + k) : (pA2[m] + (k - K1));
                a_nx[m][0] = *(const float4*)p;
                a_nx[m][1] = *(const float4*)(p + 4);
            }
            #pragma unroll
            for (int nt = 0; nt < NT; ++nt) {
                bh_nx[nt] = *(const bf16x8*)(pBh[nt] + k);
                bl_nx[nt] = *(const bf16x8*)(pBl[nt] + k);
            }
        }

        // convert A to hi/lo bf16
        bf16x8 ah[2], al[2];
        #pragma unroll
        for (int m = 0; m < 2; ++m) {
            const float f[8] = {a_c[m][0].x, a_c[m][0].y, a_c[m][0].z, a_c[m][0].w,
                                a_c[m][1].x, a_c[m][1].y, a_c[m][1].z, a_c[m][1].w};
            #pragma unroll
            for (int j = 0; j < 8; ++j) {
                const unsigned short hu = f2bf(f[j]);
                ah[m][j] = (short)hu;
                al[m][j] = (short)f2bf(f[j] - bf2f(hu));
            }
        }

        #pragma unroll
        for (int nt = 0; nt < NT; ++nt) {
            #pragma unroll
            for (int m = 0; m < 2; ++m) {
                acc[m][nt] = __builtin_amdgcn_mfma_f32_16x16x32_bf16(ah[m], bh_c[nt], acc[m][nt], 0, 0, 0);
                acc[m][nt] = __builtin_amdgcn_mfma_f32_16x16x32_bf16(ah[m], bl_c[nt], acc[m][nt], 0, 0, 0);
                acc[m][nt] = __builtin_amdgcn_mfma_f32_16x16x32_bf16(al[m], bh_c[nt], acc[m][nt], 0, 0, 0);
            }
        }
    }

    // epilogue: C/D layout col=lane&15, row=quad*4+reg
    #pragma unroll
    for (int nt = 0; nt < NT; ++nt) {
        const int gcol = col0 + nt * 16 + lrow;
        const float bsc = bias ? bias[gcol] : 0.f;
        float g = 1.f, bb = 0.f, mm = 0.f;
        if (bng) { g = bng[gcol] / sqrtf(bnv[gcol] + EPS); bb = bnb[gcol]; mm = bnm[gcol]; }
        #pragma unroll
        for (int m = 0; m < 2; ++m) {
            const int rbase = bm + wv * 32 + m * 16 + quad * 4;
            #pragma unroll
            for (int r = 0; r < 4; ++r) {
                const int grow = rbase + r;
                if (grow >= M) continue;
                float x = acc[m][nt][r] + bsc;
                if (bng) x = (x - mm) * g + bb;
                if (relu) x = fmaxf(x, 0.f);
                if (gcol < fpN) C[(size_t)grow * ldc + gcol] = x;
                if (bfout && gcol >= bfcol0)
                    bfout[(size_t)grow * 128 + (gcol - bfcol0)] = (short)f2bf(x);
            }
        }
    }
}

// ---------------------------------------------------------------------------

extern "C" void kernel_launch(void* const* d_in, const int* in_sizes, int n_in,
                              void* d_out, int out_size, void* d_ws, size_t ws_size,
                              hipStream_t stream) {
    const float* sf    = (const float*)d_in[0];
    const float* mf    = (const float*)d_in[1];
    const int*   src   = (const int*)d_in[2];
    const int*   dst   = (const int*)d_in[3];
    const float* enc_w = (const float*)d_in[4];
    const float* enc_b = (const float*)d_in[5];
    const float* s0_ws = (const float*)d_in[6];
    const float* s0_wn = (const float*)d_in[7];
    const float* s0_b  = (const float*)d_in[8];
    const float* bn0_g = (const float*)d_in[9];
    const float* bn0_b = (const float*)d_in[10];
    const float* bn0_m = (const float*)d_in[11];
    const float* bn0_v = (const float*)d_in[12];
    const float* s1_ws = (const float*)d_in[13];
    const float* s1_wn = (const float*)d_in[14];
    const float* s1_b  = (const float*)d_in[15];
    const float* bn1_g = (const float*)d_in[16];
    const float* bn1_b = (const float*)d_in[17];
    const float* bn1_m = (const float*)d_in[18];
    const float* bn1_v = (const float*)d_in[19];
    const float* rel_w = (const float*)d_in[20];
    const float* rel_b = (const float*)d_in[21];
    const float* cw1   = (const float*)d_in[22];
    const float* cb1   = (const float*)d_in[23];
    const float* cw2   = (const float*)d_in[24];
    const float* cb2   = (const float*)d_in[25];
    float* out = (float*)d_out;

    const int nn = in_sizes[0] / 128;   // 100000
    const int ne = in_sizes[2];         // 800000
    const int nb = (nn + 1023) / 1024;  // scan blocks (98)

    // workspace layout
    float* h0 = (float*)d_ws;                    // [nn,128]  h0 (live to end)
    float* h1 = h0 + (size_t)nn * 128;           // [nn,256]  h1 -> h2(ld128) | o1
    float* st = h1 + (size_t)nn * 256;           // [nn,128]  agg0 -> s1 -> r
    short* h0b = (short*)(st + (size_t)nn * 128);// [nn,128] bf16 plane of h0
    short* t1b = h0b + (size_t)nn * 128;         // [nn,128] bf16 plane of t1
    int* deg    = (int*)(t1b + (size_t)nn * 128);
    int* rowptr = deg + nn;
    int* cursor = rowptr + nn + 1;
    int* part   = cursor + nn;                   // [nb+1]
    int* eidx   = part + nb + 1;
    // bf16 weight planes (hi, lo) — transposed [N][K]
    short* wts = (short*)(eidx + ne);
    short* wt_enc_h = wts;                 short* wt_enc_l = wt_enc_h + 65536;   // [128][512]
    short* wt_s0_h  = wt_enc_l + 65536;    short* wt_s0_l  = wt_s0_h  + 65536;   // [256][256]
    short* wt_st_h  = wt_s0_l  + 65536;    short* wt_st_l  = wt_st_h  + 65536;   // [256][256]
    short* wt_rel_h = wt_st_l  + 65536;    short* wt_rel_l = wt_rel_h + 32768;   // [128][256]
    short* wt_c1_h  = wt_rel_l + 32768;    short* wt_c1_l  = wt_c1_h  + 8192;    // [64][128]
    short* wt_c2_h  = wt_c1_l  + 8192;     short* wt_c2_l  = wt_c2_h  + 2048;    // [32][64]

    const dim3 blk(256);
    const int gM = (nn + 127) / 128;    // 782 row-blocks

    // --- CSR build (parallel scan) ---
    zero_int  <<<dim3((nn + 255) / 256), blk, 0, stream>>>(deg, nn);
    count_deg <<<dim3((ne + 255) / 256), blk, 0, stream>>>(dst, deg, ne);
    scan_block<<<dim3(nb), dim3(1024), 0, stream>>>(deg, rowptr, part, nn);
    scan_part <<<dim3(1),  dim3(1024), 0, stream>>>(part, nb);
    scan_add  <<<dim3((nn + 255) / 256), blk, 0, stream>>>(part, rowptr, cursor, nn, nb);
    fill_edges<<<dim3((ne + 255) / 256), blk, 0, stream>>>(src, dst, cursor, eidx, ne);

    // --- weight prep (tiny) ---
    prep_w<<<dim3(256), blk, 0, stream>>>(enc_w, 512, 128, wt_enc_h, wt_enc_l, 512, 0);
    prep_w<<<dim3(128), blk, 0, stream>>>(s0_ws, 128, 256, wt_s0_h, wt_s0_l, 256, 0);
    prep_w<<<dim3(128), blk, 0, stream>>>(s0_wn, 128, 256, wt_s0_h, wt_s0_l, 256, 128);
    prep_w<<<dim3(128), blk, 0, stream>>>(s1_ws, 256, 128, wt_st_h, wt_st_l, 256, 0);
    prep_w<<<dim3(128), blk, 0, stream>>>(s1_wn, 256, 128, wt_st_h + (size_t)128 * 256,
                                          wt_st_l + (size_t)128 * 256, 256, 0);
    prep_w<<<dim3(128), blk, 0, stream>>>(rel_w, 256, 128, wt_rel_h, wt_rel_l, 256, 0);
    prep_w<<<dim3(32),  blk, 0, stream>>>(cw1, 128, 64, wt_c1_h, wt_c1_l, 128, 0);
    prep_w<<<dim3(8),   blk, 0, stream>>>(cw2, 64, 32, wt_c2_h, wt_c2_l, 64, 0);

    // --- h0 = relu(concat(sf,mf) @ enc_w + enc_b); also bf16 plane h0b ---
    gemm_mfma<8, 128, 384><<<dim3(1, gM), blk, 0, stream>>>(
        sf, 128, mf, 384, wt_enc_h, wt_enc_l, enc_b,
        nullptr, nullptr, nullptr, nullptr, 1, h0, 128, 128, h0b, 0, nn);

    // --- agg0 = mean_neigh(h0) -> st (bf16 gather) ---
    agg_mean_bf<<<dim3((nn + 3) / 4), blk, 0, stream>>>(
        h0b, rowptr, eidx, nullptr, 0, nullptr,
        nullptr, nullptr, nullptr, nullptr, st, 128, nn);

    // --- h1 = relu(bn0(h0@ws0 + agg0@wn0 + b0)) ---
    gemm_mfma<8, 128, 128><<<dim3(2, gM), blk, 0, stream>>>(
        h0, 128, st, 128, wt_s0_h, wt_s0_l, s0_b,
        bn0_g, bn0_b, bn0_m, bn0_v, 1, h1, 256, 256, nullptr, 0, nn);

    // --- [s1 | t1] = h1 @ [ws1 | wn1]; s1 fp32 -> st, t1 bf16 -> t1b ---
    gemm_mfma<8, 256, 0><<<dim3(2, gM), blk, 0, stream>>>(
        h1, 256, nullptr, 0, wt_st_h, wt_st_l, nullptr,
        nullptr, nullptr, nullptr, nullptr, 0, st, 128, 128, t1b, 128, nn);

    // --- h2 = relu(bn1(s1 + mean_neigh(t1) + b1)) -> h1[0:nn*128] (ld128) ---
    agg_mean_bf<<<dim3((nn + 3) / 4), blk, 0, stream>>>(
        t1b, rowptr, eidx, st, 128, s1_b,
        bn1_g, bn1_b, bn1_m, bn1_v, h1, 128, nn);

    // --- r = relu(h0@rel_w[:128] + h2@rel_w[128:] + rel_b) -> st ---
    gemm_mfma<8, 128, 128><<<dim3(1, gM), blk, 0, stream>>>(
        h0, 128, h1, 128, wt_rel_h, wt_rel_l, rel_b,
        nullptr, nullptr, nullptr, nullptr, 1, st, 128, 128, nullptr, 0, nn);

    // --- o1 = relu(r@cls_w1 + cb1) -> h1 + nn*128 ([nn,64]) ---
    gemm_mfma<4, 128, 0><<<dim3(1, gM), blk, 0, stream>>>(
        st, 128, nullptr, 0, wt_c1_h, wt_c1_l, cb1,
        nullptr, nullptr, nullptr, nullptr, 1, h1 + (size_t)nn * 128, 64, 64,
        nullptr, 0, nn);

    // --- out = o1@cls_w2 + cb2 -> d_out [nn,32] ---
    gemm_mfma<2, 64, 0><<<dim3(1, gM), blk, 0, stream>>>(
        h1 + (size_t)nn * 128, 64, nullptr, 0, wt_c2_h, wt_c2_l, cb2,
        nullptr, nullptr, nullptr, nullptr, 0, out, 32, 32, nullptr, 0, nn);
}

// Round 6
// 1073.366 us; speedup vs baseline: 1.3795x; 1.2627x over previous
//
#include <hip/hip_runtime.h>
#include <math.h>

// ---------------------------------------------------------------------------
// MultiModalGraphSAGE — R6: all-bf16 activation planes + split-bf16 weights.
// R5 post-mortem: GEMMs HBM-latency-bound (~1.3 B/cyc/CU in flight) and
// VALU-chained on fp32->hi/lo split. R6: activations stored bf16 (epilogues
// write bf16 planes), A loads issue for ALL K up-front (K<=256 -> 8 chunks,
// 64 VGPR), B dbuf 1 chunk ahead from L2, 2 MFMAs/tile (A@Whi + A@Wlo).
// enc keeps fp32 inputs with a 4-chunk rolling window + in-reg convert.
// ---------------------------------------------------------------------------

#define EPS 1e-5f

typedef __attribute__((ext_vector_type(8))) short bf16x8;
typedef __attribute__((ext_vector_type(4))) float f32x4;

__device__ inline unsigned short f2bf(float x) {
    unsigned u = __float_as_uint(x);
    u += 0x7fff + ((u >> 16) & 1);          // RNE to bf16
    return (unsigned short)(u >> 16);
}
__device__ inline float bf2f(unsigned short h) {
    return __uint_as_float(((unsigned)h) << 16);
}
__device__ inline unsigned packbf(float x, float y) {
    return (unsigned)f2bf(x) | ((unsigned)f2bf(y) << 16);
}

// ---------------- CSR build ----------------

__global__ void zero_int(int* __restrict__ p, int n) {
    int i = blockIdx.x * 256 + threadIdx.x;
    if (i < n) p[i] = 0;
}

__global__ void count_deg(const int* __restrict__ dst, int* __restrict__ deg, int e) {
    int i = blockIdx.x * 256 + threadIdx.x;
    if (i < e) atomicAdd(&deg[dst[i]], 1);
}

__global__ __launch_bounds__(1024)
void scan_block(const int* __restrict__ deg, int* __restrict__ rowptr,
                int* __restrict__ part, int n) {
    __shared__ int buf[1024];
    const int tid = threadIdx.x;
    const int i = blockIdx.x * 1024 + tid;
    const int v = (i < n) ? deg[i] : 0;
    buf[tid] = v;
    __syncthreads();
    #pragma unroll 1
    for (int off = 1; off < 1024; off <<= 1) {
        int t = (tid >= off) ? buf[tid - off] : 0;
        __syncthreads();
        buf[tid] += t;
        __syncthreads();
    }
    if (i < n) rowptr[i] = buf[tid] - v;          // local exclusive
    if (tid == 1023) part[blockIdx.x] = buf[1023];
}

__global__ __launch_bounds__(1024)
void scan_part(int* __restrict__ part, int nb) {
    __shared__ int buf[1024];
    const int tid = threadIdx.x;
    const int v = (tid < nb) ? part[tid] : 0;
    buf[tid] = v;
    __syncthreads();
    #pragma unroll 1
    for (int off = 1; off < 1024; off <<= 1) {
        int t = (tid >= off) ? buf[tid - off] : 0;
        __syncthreads();
        buf[tid] += t;
        __syncthreads();
    }
    if (tid < nb) part[tid] = buf[tid] - v;       // exclusive
    if (tid == 1023) part[nb] = buf[1023];        // grand total
}

__global__ void scan_add(const int* __restrict__ part, int* __restrict__ rowptr,
                         int* __restrict__ cursor, int n, int nb) {
    int i = blockIdx.x * 256 + threadIdx.x;
    if (i < n) {
        int v = rowptr[i] + part[i >> 10];
        rowptr[i] = v;
        cursor[i] = v;
    }
    if (i == 0) rowptr[n] = part[nb];
}

__global__ void fill_edges(const int* __restrict__ src, const int* __restrict__ dst,
                           int* __restrict__ cursor, int* __restrict__ eidx, int e) {
    int i = blockIdx.x * 256 + threadIdx.x;
    if (i < e) {
        int pos = atomicAdd(&cursor[dst[i]], 1);
        eidx[pos] = src[i];
    }
}

// ---------------- weight prep: W[K][N] fp32 -> Wt hi/lo [N][ldt] bf16 -------

__global__ void prep_w(const float* __restrict__ W, int K, int N,
                       short* __restrict__ hi, short* __restrict__ lo,
                       int ldt, int koff) {
    int i = blockIdx.x * 256 + threadIdx.x;
    if (i >= K * N) return;
    int k = i / N, n = i - k * N;
    float x = W[i];
    unsigned short h = f2bf(x);
    unsigned short l = f2bf(x - bf2f(h));
    size_t o = (size_t)n * ldt + koff + k;
    hi[o] = (short)h;
    lo[o] = (short)l;
}

// ---------------- mean aggregation (bf16 in, bf16 out), one wave per node ---

__global__ __launch_bounds__(256)
void agg_mean_bb(const short* __restrict__ featb,
                 const int* __restrict__ rowptr, const int* __restrict__ eidx,
                 short* __restrict__ outb, int n) {
    const int node = blockIdx.x * 4 + (threadIdx.x >> 6);
    if (node >= n) return;
    const int lane = threadIdx.x & 63;
    const int beg = rowptr[node], end = rowptr[node + 1];
    float sx = 0.f, sy = 0.f;
    for (int e = beg; e < end; ++e) {
        const unsigned v =
            ((const unsigned*)(featb + (size_t)eidx[e] * 128))[lane];
        sx += __uint_as_float(v << 16);
        sy += __uint_as_float(v & 0xffff0000u);
    }
    const float inv = 1.0f / fmaxf((float)(end - beg), 1.0f);
    ((unsigned*)(outb + (size_t)node * 128))[lane] = packbf(sx * inv, sy * inv);
}

// sage1 combine: h2 = relu(bn1(s1 + mean_neigh(t1) + b1)), bf16 out
__global__ __launch_bounds__(256)
void agg_combine_bb(const short* __restrict__ featb,
                    const int* __restrict__ rowptr, const int* __restrict__ eidx,
                    const float* __restrict__ s1,          // [n,128] fp32
                    const float* __restrict__ bias,
                    const float* __restrict__ bng, const float* __restrict__ bnb,
                    const float* __restrict__ bnm, const float* __restrict__ bnv,
                    short* __restrict__ outb, int n) {
    const int node = blockIdx.x * 4 + (threadIdx.x >> 6);
    if (node >= n) return;
    const int lane = threadIdx.x & 63;
    const int beg = rowptr[node], end = rowptr[node + 1];
    float sx = 0.f, sy = 0.f;
    for (int e = beg; e < end; ++e) {
        const unsigned v =
            ((const unsigned*)(featb + (size_t)eidx[e] * 128))[lane];
        sx += __uint_as_float(v << 16);
        sy += __uint_as_float(v & 0xffff0000u);
    }
    const float inv = 1.0f / fmaxf((float)(end - beg), 1.0f);
    sx *= inv; sy *= inv;
    const int c = lane * 2;
    const float2 s = ((const float2*)(s1 + (size_t)node * 128))[lane];
    float v0 = s.x + sx + bias[c];
    float v1 = s.y + sy + bias[c + 1];
    v0 = (v0 - bnm[c])     * (bng[c]     / sqrtf(bnv[c]     + EPS)) + bnb[c];
    v1 = (v1 - bnm[c + 1]) * (bng[c + 1] / sqrtf(bnv[c + 1] + EPS)) + bnb[c + 1];
    ((unsigned*)(outb + (size_t)node * 128))[lane] =
        packbf(fmaxf(v0, 0.f), fmaxf(v1, 0.f));
}

// ---------------- MFMA GEMM: bf16 A (or fp32 converted), split-bf16 W -------
// Block: 256 thr = 4 waves, 2 m-tiles/wave (128 rows). NT n-tiles of 16.
// A loads for a whole window (all K when K<=256) issue up-front; B (L2-hot)
// double-buffered 1 chunk ahead. 2 MFMAs per tile: A@Whi + A@Wlo.
// Output: fp32 C for cols < fpN; bf16 plane Cb for cols >= bfcol0.
template<int NT, int K1, int K2, bool AF32>
__global__ __launch_bounds__(256)
void gemm_bf(const void* __restrict__ A1v, int lda1,
             const void* __restrict__ A2v, int lda2,
             const short* __restrict__ Wt_hi, const short* __restrict__ Wt_lo,
             const float* __restrict__ bias,
             const float* __restrict__ bng, const float* __restrict__ bnb,
             const float* __restrict__ bnm, const float* __restrict__ bnv,
             int relu,
             float* __restrict__ Cf, int fpN, int ldc,
             short* __restrict__ Cb, int bfcol0, int ldcb,
             int M) {
    constexpr int K  = K1 + K2;                  // multiple of 32
    constexpr int NC = K / 32;                   // chunks
    constexpr int CW = AF32 ? (NC < 4 ? NC : 4) : (NC < 8 ? NC : 8);
    constexpr int NW = NC / CW;                  // windows
    const int tid  = threadIdx.x;
    const int lane = tid & 63;
    const int wv   = tid >> 6;
    const int bm   = blockIdx.y * 128;
    const int col0 = blockIdx.x * (NT * 16);
    const int lrow = lane & 15;
    const int quad = lane >> 4;
    const int kin  = quad * 8;

    const short* pA1s[2]; const short* pA2s[2];
    const float* pA1f[2]; const float* pA2f[2];
    #pragma unroll
    for (int m = 0; m < 2; ++m) {
        const int r = min(bm + wv * 32 + m * 16 + lrow, M - 1);
        if constexpr (AF32) {
            pA1f[m] = (const float*)A1v + (size_t)r * lda1 + kin;
            pA2f[m] = (K2 > 0) ? ((const float*)A2v + (size_t)r * lda2 + kin) : nullptr;
        } else {
            pA1s[m] = (const short*)A1v + (size_t)r * lda1 + kin;
            pA2s[m] = (K2 > 0) ? ((const short*)A2v + (size_t)r * lda2 + kin) : nullptr;
        }
    }

    const short* pBh[NT];
    const short* pBl[NT];
    #pragma unroll
    for (int nt = 0; nt < NT; ++nt) {
        const size_t wo = (size_t)(col0 + nt * 16 + lrow) * K + kin;
        pBh[nt] = Wt_hi + wo;
        pBl[nt] = Wt_lo + wo;
    }

    f32x4 acc[2][NT];
    #pragma unroll
    for (int m = 0; m < 2; ++m)
        #pragma unroll
        for (int nt = 0; nt < NT; ++nt)
            acc[m][nt] = (f32x4){0.f, 0.f, 0.f, 0.f};

    // B double buffer: preload chunk 0
    bf16x8 bh[2][NT], bl[2][NT];
    #pragma unroll
    for (int nt = 0; nt < NT; ++nt) {
        bh[0][nt] = *(const bf16x8*)(pBh[nt]);
        bl[0][nt] = *(const bf16x8*)(pBl[nt]);
    }

    #pragma unroll
    for (int w = 0; w < NW; ++w) {
        // ---- A window: issue all loads for CW chunks up-front ----
        bf16x8 aw[2][CW];
        float4 awf[2][CW][2];
        #pragma unroll
        for (int i = 0; i < CW; ++i) {
            const int k = (w * CW + i) * 32;
            #pragma unroll
            for (int m = 0; m < 2; ++m) {
                if constexpr (AF32) {
                    const float* p = (k < K1) ? (pA1f[m] + k) : (pA2f[m] + (k - K1));
                    awf[m][i][0] = *(const float4*)p;
                    awf[m][i][1] = *(const float4*)(p + 4);
                } else {
                    const short* p = (k < K1) ? (pA1s[m] + k) : (pA2s[m] + (k - K1));
                    aw[m][i] = *(const bf16x8*)p;
                }
            }
        }
        #pragma unroll
        for (int i = 0; i < CW; ++i) {
            const int c = w * CW + i;
            const int cur = c & 1, nxt = cur ^ 1;
            if (c + 1 < NC) {                    // prefetch next B chunk
                const int k2 = (c + 1) * 32;
                #pragma unroll
                for (int nt = 0; nt < NT; ++nt) {
                    bh[nxt][nt] = *(const bf16x8*)(pBh[nt] + k2);
                    bl[nxt][nt] = *(const bf16x8*)(pBl[nt] + k2);
                }
            }
            bf16x8 a[2];
            #pragma unroll
            for (int m = 0; m < 2; ++m) {
                if constexpr (AF32) {
                    const float f[8] = {awf[m][i][0].x, awf[m][i][0].y,
                                        awf[m][i][0].z, awf[m][i][0].w,
                                        awf[m][i][1].x, awf[m][i][1].y,
                                        awf[m][i][1].z, awf[m][i][1].w};
                    #pragma unroll
                    for (int j = 0; j < 8; ++j) a[m][j] = (short)f2bf(f[j]);
                } else {
                    a[m] = aw[m][i];
                }
            }
            #pragma unroll
            for (int nt = 0; nt < NT; ++nt) {
                #pragma unroll
                for (int m = 0; m < 2; ++m) {
                    acc[m][nt] = __builtin_amdgcn_mfma_f32_16x16x32_bf16(a[m], bh[cur][nt], acc[m][nt], 0, 0, 0);
                    acc[m][nt] = __builtin_amdgcn_mfma_f32_16x16x32_bf16(a[m], bl[cur][nt], acc[m][nt], 0, 0, 0);
                }
            }
        }
    }

    // epilogue: C/D layout col=lane&15, row=quad*4+reg
    #pragma unroll
    for (int nt = 0; nt < NT; ++nt) {
        const int gcol = col0 + nt * 16 + lrow;
        const float bsc = bias ? bias[gcol] : 0.f;
        float g = 1.f, bb = 0.f, mm = 0.f;
        if (bng) { g = bng[gcol] / sqrtf(bnv[gcol] + EPS); bb = bnb[gcol]; mm = bnm[gcol]; }
        #pragma unroll
        for (int m = 0; m < 2; ++m) {
            const int rbase = bm + wv * 32 + m * 16 + quad * 4;
            #pragma unroll
            for (int r = 0; r < 4; ++r) {
                const int grow = rbase + r;
                if (grow >= M) continue;
                float x = acc[m][nt][r] + bsc;
                if (bng) x = (x - mm) * g + bb;
                if (relu) x = fmaxf(x, 0.f);
                if (gcol < fpN) Cf[(size_t)grow * ldc + gcol] = x;
                if (Cb && gcol >= bfcol0)
                    Cb[(size_t)grow * ldcb + (gcol - bfcol0)] = (short)f2bf(x);
            }
        }
    }
}

// ---------------------------------------------------------------------------

extern "C" void kernel_launch(void* const* d_in, const int* in_sizes, int n_in,
                              void* d_out, int out_size, void* d_ws, size_t ws_size,
                              hipStream_t stream) {
    const float* sf    = (const float*)d_in[0];
    const float* mf    = (const float*)d_in[1];
    const int*   src   = (const int*)d_in[2];
    const int*   dst   = (const int*)d_in[3];
    const float* enc_w = (const float*)d_in[4];
    const float* enc_b = (const float*)d_in[5];
    const float* s0_ws = (const float*)d_in[6];
    const float* s0_wn = (const float*)d_in[7];
    const float* s0_b  = (const float*)d_in[8];
    const float* bn0_g = (const float*)d_in[9];
    const float* bn0_b = (const float*)d_in[10];
    const float* bn0_m = (const float*)d_in[11];
    const float* bn0_v = (const float*)d_in[12];
    const float* s1_ws = (const float*)d_in[13];
    const float* s1_wn = (const float*)d_in[14];
    const float* s1_b  = (const float*)d_in[15];
    const float* bn1_g = (const float*)d_in[16];
    const float* bn1_b = (const float*)d_in[17];
    const float* bn1_m = (const float*)d_in[18];
    const float* bn1_v = (const float*)d_in[19];
    const float* rel_w = (const float*)d_in[20];
    const float* rel_b = (const float*)d_in[21];
    const float* cw1   = (const float*)d_in[22];
    const float* cb1   = (const float*)d_in[23];
    const float* cw2   = (const float*)d_in[24];
    const float* cb2   = (const float*)d_in[25];
    float* out = (float*)d_out;

    const int nn = in_sizes[0] / 128;   // 100000
    const int ne = in_sizes[2];         // 800000
    const int nb = (nn + 1023) / 1024;  // scan blocks (98)

    // workspace layout
    float* st    = (float*)d_ws;                       // s1 fp32 [nn,128]
    short* h0b   = (short*)(st + (size_t)nn * 128);    // [nn,128]
    short* h1b   = h0b + (size_t)nn * 128;             // [nn,256]
    short* agg0b = h1b + (size_t)nn * 256;             // [nn,128]; reused as o1b
    short* t1b   = agg0b + (size_t)nn * 128;           // [nn,128]; reused as rb
    short* h2b   = t1b + (size_t)nn * 128;             // [nn,128]
    short* o1b   = agg0b;                              // [nn,64] (agg0b dead)
    short* rb    = t1b;                                // [nn,128] (t1b dead)
    int* deg    = (int*)(h2b + (size_t)nn * 128);
    int* rowptr = deg + nn;
    int* cursor = rowptr + nn + 1;
    int* part   = cursor + nn;                         // [nb+1]
    int* eidx   = part + nb + 1;
    // bf16 weight planes (hi, lo) — transposed [N][K]
    short* wts = (short*)(eidx + ne);
    short* wt_enc_h = wts;                 short* wt_enc_l = wt_enc_h + 65536;   // [128][512]
    short* wt_s0_h  = wt_enc_l + 65536;    short* wt_s0_l  = wt_s0_h  + 65536;   // [256][256]
    short* wt_st_h  = wt_s0_l  + 65536;    short* wt_st_l  = wt_st_h  + 65536;   // [256][256]
    short* wt_rel_h = wt_st_l  + 65536;    short* wt_rel_l = wt_rel_h + 32768;   // [128][256]
    short* wt_c1_h  = wt_rel_l + 32768;    short* wt_c1_l  = wt_c1_h  + 8192;    // [64][128]
    short* wt_c2_h  = wt_c1_l  + 8192;     short* wt_c2_l  = wt_c2_h  + 2048;    // [32][64]

    const dim3 blk(256);
    const int gM = (nn + 127) / 128;    // 782 row-blocks

    // --- CSR build (parallel scan) ---
    zero_int  <<<dim3((nn + 255) / 256), blk, 0, stream>>>(deg, nn);
    count_deg <<<dim3((ne + 255) / 256), blk, 0, stream>>>(dst, deg, ne);
    scan_block<<<dim3(nb), dim3(1024), 0, stream>>>(deg, rowptr, part, nn);
    scan_part <<<dim3(1),  dim3(1024), 0, stream>>>(part, nb);
    scan_add  <<<dim3((nn + 255) / 256), blk, 0, stream>>>(part, rowptr, cursor, nn, nb);
    fill_edges<<<dim3((ne + 255) / 256), blk, 0, stream>>>(src, dst, cursor, eidx, ne);

    // --- weight prep (tiny) ---
    prep_w<<<dim3(256), blk, 0, stream>>>(enc_w, 512, 128, wt_enc_h, wt_enc_l, 512, 0);
    prep_w<<<dim3(128), blk, 0, stream>>>(s0_ws, 128, 256, wt_s0_h, wt_s0_l, 256, 0);
    prep_w<<<dim3(128), blk, 0, stream>>>(s0_wn, 128, 256, wt_s0_h, wt_s0_l, 256, 128);
    prep_w<<<dim3(128), blk, 0, stream>>>(s1_ws, 256, 128, wt_st_h, wt_st_l, 256, 0);
    prep_w<<<dim3(128), blk, 0, stream>>>(s1_wn, 256, 128, wt_st_h + (size_t)128 * 256,
                                          wt_st_l + (size_t)128 * 256, 256, 0);
    prep_w<<<dim3(128), blk, 0, stream>>>(rel_w, 256, 128, wt_rel_h, wt_rel_l, 256, 0);
    prep_w<<<dim3(32),  blk, 0, stream>>>(cw1, 128, 64, wt_c1_h, wt_c1_l, 128, 0);
    prep_w<<<dim3(8),   blk, 0, stream>>>(cw2, 64, 32, wt_c2_h, wt_c2_l, 64, 0);

    // --- h0 = relu(concat(sf,mf) @ enc_w + enc_b) -> h0b bf16 ---
    gemm_bf<4, 128, 384, true><<<dim3(2, gM), blk, 0, stream>>>(
        sf, 128, mf, 384, wt_enc_h, wt_enc_l, enc_b,
        nullptr, nullptr, nullptr, nullptr, 1,
        nullptr, 0, 0, h0b, 0, 128, nn);

    // --- agg0 = mean_neigh(h0b) -> agg0b bf16 ---
    agg_mean_bb<<<dim3((nn + 3) / 4), blk, 0, stream>>>(
        h0b, rowptr, eidx, agg0b, nn);

    // --- h1 = relu(bn0(h0@ws0 + agg0@wn0 + b0)) -> h1b bf16 ---
    gemm_bf<4, 128, 128, false><<<dim3(4, gM), blk, 0, stream>>>(
        h0b, 128, agg0b, 128, wt_s0_h, wt_s0_l, s0_b,
        bn0_g, bn0_b, bn0_m, bn0_v, 1,
        nullptr, 0, 0, h1b, 0, 256, nn);

    // --- [s1 | t1] = h1 @ [ws1 | wn1]; s1 fp32 -> st, t1 bf16 -> t1b ---
    gemm_bf<4, 256, 0, false><<<dim3(4, gM), blk, 0, stream>>>(
        h1b, 256, nullptr, 0, wt_st_h, wt_st_l, nullptr,
        nullptr, nullptr, nullptr, nullptr, 0,
        st, 128, 128, t1b, 128, 128, nn);

    // --- h2 = relu(bn1(s1 + mean_neigh(t1) + b1)) -> h2b bf16 ---
    agg_combine_bb<<<dim3((nn + 3) / 4), blk, 0, stream>>>(
        t1b, rowptr, eidx, st, s1_b,
        bn1_g, bn1_b, bn1_m, bn1_v, h2b, nn);

    // --- r = relu(h0@rel_w[:128] + h2@rel_w[128:] + rel_b) -> rb bf16 ---
    gemm_bf<4, 128, 128, false><<<dim3(2, gM), blk, 0, stream>>>(
        h0b, 128, h2b, 128, wt_rel_h, wt_rel_l, rel_b,
        nullptr, nullptr, nullptr, nullptr, 1,
        nullptr, 0, 0, rb, 0, 128, nn);

    // --- o1 = relu(r@cls_w1 + cb1) -> o1b bf16 [nn,64] ---
    gemm_bf<4, 128, 0, false><<<dim3(1, gM), blk, 0, stream>>>(
        rb, 128, nullptr, 0, wt_c1_h, wt_c1_l, cb1,
        nullptr, nullptr, nullptr, nullptr, 1,
        nullptr, 0, 0, o1b, 0, 64, nn);

    // --- out = o1@cls_w2 + cb2 -> d_out fp32 [nn,32] ---
    gemm_bf<2, 64, 0, false><<<dim3(1, gM), blk, 0, stream>>>(
        o1b, 64, nullptr, 0, wt_c2_h, wt_c2_l, cb2,
        nullptr, nullptr, nullptr, nullptr, 0,
        out, 32, 32, nullptr, 0, 0, nn);
}